// Round 15
// baseline (174.072 us; speedup 1.0000x reference)
//
#include <hip/hip_runtime.h>
#include <cstdint>
#include <cstddef>

// Problem constants (B=32, D=256, H=32, W=32, K=1024), N = B*H*W = 32768.
// MFMA path: fp32 -> 3x bf16 split; 6 concat-K segments -> bf16 GEMM
// M=32768 N=1024 K=1536; error ~ fp32 accumulation (numpy-grade).
//
// FINAL CONFIG = r9 (best measured: GEMM 114.9µs, total 156µs, MfmaUtil 38%,
// 0 bank conflicts, VGPR 124 + 128 AGPR, no spill) + r12's fused init.
// Post-r9 structural attempts all failed and are documented:
//   r10 fat-phase: spilled (acc[8][4]=128 AGPR leaves no headroom at the
//       256-reg/wave cap; compiler pins VGPR=128 and spills instead of
//       raising allocation despite launch_bounds).
//   r11/r12 barrier-cut: spilled / neutral — cross-region live ranges.
//   r13 64x64 wave tiles + 1 barrier/tile: clean but LDS-traffic-bound
//       (per-wave frag traffic (1/Mw+1/Nw) B/FLOP worsens), 142µs.
//   r14 register X/Y frag dbuf overlap: clean, 130µs — overhead/tile is
//       ~2300-3300cyc regardless of barrier count or read/MFMA overlap.
// Conclusion: r9's 128x64 wave tile (max tile under reg cap, min LDS
// traffic) dominates; further gains need the full HK/m201 co-designed
// 8-phase template (62% MfmaUtil), which does not graft piecewise.

typedef __attribute__((ext_vector_type(8))) short bf16x8;
typedef __attribute__((ext_vector_type(4))) float f32x4;

#define GL2LDS(g, l) __builtin_amdgcn_global_load_lds( \
    (__attribute__((address_space(1))) const void*)(g), \
    (__attribute__((address_space(3))) void*)(l), 16, 0, 0)

__device__ __forceinline__ unsigned short rne_bf16(float f) {
    unsigned u = __float_as_uint(f);
    return (unsigned short)((u + 0x7FFFu + ((u >> 16) & 1u)) >> 16);
}
__device__ __forceinline__ float bf16_to_f(unsigned short h) {
    return __uint_as_float((unsigned)h << 16);
}

// ---------------------------------------------------------------------------
// codebook row norms ||c_k||^2  (summation order feeds argmin -- unchanged)
// ---------------------------------------------------------------------------
__global__ __launch_bounds__(256)
void vq_cnorm_kernel(const float* __restrict__ cb, float* __restrict__ cnorm)
{
    const int k = blockIdx.x * 256 + threadIdx.x;  // grid=4
    const float4* row = reinterpret_cast<const float4*>(cb + (size_t)k * 256);
    float s0 = 0.f, s1 = 0.f, s2 = 0.f, s3 = 0.f;
#pragma unroll 8
    for (int i = 0; i < 64; ++i) {
        float4 v = row[i];
        s0 = fmaf(v.x, v.x, s0);
        s1 = fmaf(v.y, v.y, s1);
        s2 = fmaf(v.z, v.z, s2);
        s3 = fmaf(v.w, v.w, s3);
    }
    cnorm[k] = (s0 + s1) + (s2 + s3);
}

// ---------------------------------------------------------------------------
// codebook split + packed/loss init (memset fusion, benched r12): grid 256
// ---------------------------------------------------------------------------
__global__ __launch_bounds__(256)
void vq_csplit_kernel(const float* __restrict__ cb, unsigned short* __restrict__ c0,
                      unsigned short* __restrict__ c1, unsigned short* __restrict__ c2,
                      unsigned long long* __restrict__ packed, float* __restrict__ loss)
{
    const int b = blockIdx.x, t = threadIdx.x;
    const int idx = b * 256 + t;
    if (t < 128) packed[b * 128 + t] = 0xFFFFFFFFFFFFFFFFull;
    if (b == 0 && t == 255) *loss = 0.f;

    float4 v = reinterpret_cast<const float4*>(cb)[idx];
    float f[4] = { v.x, v.y, v.z, v.w };
    ushort4 h0, h1, h2;
    unsigned short* p0[4] = { &h0.x, &h0.y, &h0.z, &h0.w };
    unsigned short* p1[4] = { &h1.x, &h1.y, &h1.z, &h1.w };
    unsigned short* p2[4] = { &h2.x, &h2.y, &h2.z, &h2.w };
#pragma unroll
    for (int j = 0; j < 4; ++j) {
        unsigned short b0 = rne_bf16(f[j]); float r1 = f[j] - bf16_to_f(b0);
        unsigned short b1 = rne_bf16(r1);   float r2 = r1 - bf16_to_f(b1);
        unsigned short b2 = rne_bf16(r2);
        *p0[j] = b0; *p1[j] = b1; *p2[j] = b2;
    }
    reinterpret_cast<ushort4*>(c0)[idx] = h0;
    reinterpret_cast<ushort4*>(c1)[idx] = h1;
    reinterpret_cast<ushort4*>(c2)[idx] = h2;
}

// ---------------------------------------------------------------------------
// z split+transpose: z[b][d][hw] fp32 -> z0,z1,z2 bf16 [n][d]
// ---------------------------------------------------------------------------
__global__ __launch_bounds__(256)
void vq_zsplit_kernel(const float* __restrict__ z, unsigned short* __restrict__ z0,
                      unsigned short* __restrict__ z1, unsigned short* __restrict__ z2)
{
    __shared__ float zl[64 * 264];
    const int t = threadIdx.x, blk = blockIdx.x;        // 512 blocks
    const int b = blk >> 4, hw0 = (blk & 15) << 6;
    const float* zb = z + ((size_t)b << 18) + hw0;
#pragma unroll 8
    for (int i = 0; i < 64; ++i) {
        int idx = i * 256 + t;
        int d = idx >> 6, hwl = idx & 63;
        zl[hwl * 264 + d] = zb[(size_t)d * 1024 + hwl];
    }
    __syncthreads();
    const int n0 = (b << 10) + hw0;
#pragma unroll
    for (int p = 0; p < 8; ++p) {
        const int hwl = p * 8 + (t >> 5);
        const int d0 = (t & 31) * 8;
        const float* src = &zl[hwl * 264 + d0];
        unsigned short h0[8], h1[8], h2[8];
#pragma unroll
        for (int j = 0; j < 8; ++j) {
            float f = src[j];
            unsigned short b0 = rne_bf16(f);  float r1 = f - bf16_to_f(b0);
            unsigned short b1 = rne_bf16(r1); float r2 = r1 - bf16_to_f(b1);
            unsigned short b2 = rne_bf16(r2);
            h0[j] = b0; h1[j] = b1; h2[j] = b2;
        }
        const size_t o = (size_t)(n0 + hwl) * 256 + d0;
        ushort4 a;
        a = ushort4{h0[0],h0[1],h0[2],h0[3]}; *reinterpret_cast<ushort4*>(z0 + o)     = a;
        a = ushort4{h0[4],h0[5],h0[6],h0[7]}; *reinterpret_cast<ushort4*>(z0 + o + 4) = a;
        a = ushort4{h1[0],h1[1],h1[2],h1[3]}; *reinterpret_cast<ushort4*>(z1 + o)     = a;
        a = ushort4{h1[4],h1[5],h1[6],h1[7]}; *reinterpret_cast<ushort4*>(z1 + o + 4) = a;
        a = ushort4{h2[0],h2[1],h2[2],h2[3]}; *reinterpret_cast<ushort4*>(z2 + o)     = a;
        a = ushort4{h2[4],h2[5],h2[6],h2[7]}; *reinterpret_cast<ushort4*>(z2 + o + 4) = a;
    }
}

// ---------------------------------------------------------------------------
// MFMA GEMM + fused argmin — r9 VERBATIM (measured 114.9µs, MfmaUtil 38%).
// 256² tile, 8 waves (2wr x 4wc), per-wave 128x64 (acc[8][4] = 128 AGPR),
// 4 thin phases/K-tile, counted vmcnt(4), double-buffered LDS 128KB.
//
// Swizzle (0 conflicts, r9-verified): planes [rows][32] bf16 = 64B rows;
// bank = (row&1)*16 + slot*4; store chunk c of row r at slot c ^ ((r>>1)&3)
// (row bits 1-2; bit 0 already moves the bank half). gl2lds writes linearly
// -> GLOBAL source chunk pre-swizzled (selem); ds_read same XOR (fco).
// 16-lane phase covers all 8 (parity,slot) bank groups exactly 2x = floor.
// ---------------------------------------------------------------------------
__global__ __launch_bounds__(512, 2)
void vq_mfma_argmin_kernel(const unsigned short* __restrict__ zp,
                           const unsigned short* __restrict__ cp,
                           const float* __restrict__ cnorm,
                           unsigned long long* __restrict__ packed)
{
    __shared__ unsigned short Ld[2][2][2][256 * 32];   // 128KB

    const int tid = threadIdx.x, l = tid & 63, w = tid >> 6;
    const int wr = w >> 2, wc = w & 3;                 // 2 x 4 wave grid
    const int nid = ((blockIdx.x & 7) << 6) | (blockIdx.x >> 3);  // XCD swizzle (512%8==0)
    const int bm = nid >> 2, bn = nid & 3;             // 128 x 4 tiles
    const int arow = bm * 256, brow = bn * 256;

    f32x4 acc[8][4];
#pragma unroll
    for (int m = 0; m < 8; ++m)
#pragma unroll
        for (int n = 0; n < 4; ++n) acc[m][n] = f32x4{0.f, 0.f, 0.f, 0.f};

    // staging lane geometry: lane l -> row l>>2, slot l&3; source chunk
    // pre-swizzled by row bits 1-2 ((l>>3)&3) so stored slot = c ^ ((r>>1)&3)
    const int srow  = l >> 2;
    const int selem = (((l & 3) ^ ((l >> 3) & 3))) << 3;

    // fragment-read: chunk hi4 of row r at slot hi4 ^ ((r>>1)&3); r ≡ lo16 (16)
    const int lo16 = l & 15, hi4 = l >> 4;
    const int fco = ((hi4 ^ ((lo16 >> 1) & 3))) << 3;

    // segment tables packed as nibbles: A {0,1,2,0,1,0}, B {0,0,0,1,1,2}
#define STAGE(tt, mat, kk) do {                                               \
    const int seg_ = (tt) >> 2;                                               \
    const unsigned short* S_ = (mat)                                          \
        ? cp + (size_t)((0x211000 >> (seg_ << 2)) & 3) * 262144u              \
        : zp + (size_t)((0x010210 >> (seg_ << 2)) & 3) * 8388608u;            \
    const int R_  = (mat) ? brow : arow;                                      \
    const int KO_ = (((tt) & 3) << 6) + ((kk) << 5) + selem;                  \
    GL2LDS(S_ + (size_t)(R_ + (w * 2 + 0) * 16 + srow) * 256 + KO_,           \
           &Ld[(tt) & 1][mat][kk][(w * 2 + 0) * 512]);                        \
    GL2LDS(S_ + (size_t)(R_ + (w * 2 + 1) * 16 + srow) * 256 + KO_,           \
           &Ld[(tt) & 1][mat][kk][(w * 2 + 1) * 512]);                        \
} while (0)

#define VM4  asm volatile("s_waitcnt vmcnt(4)"  ::: "memory")
#define VM0  asm volatile("s_waitcnt vmcnt(0)"  ::: "memory")
#define NOPS ((void)0)
#define SBAR do { asm volatile("" ::: "memory");                              \
                  __builtin_amdgcn_s_barrier();                               \
                  __builtin_amdgcn_sched_barrier(0); } while (0)

    bf16x8 bfr0, bfr1, bfr2, bfr3;   // B frags, loaded at mh==0, reused mh==1

#define PH(t, mh, kk, STAGESTMT, VMSTMT) do {                                 \
    const unsigned short* Ap_ = &Ld[(t) & 1][0][kk][0];                       \
    const unsigned short* Bp_ = &Ld[(t) & 1][1][kk][0];                       \
    bf16x8 a0, a1, a2, a3;                                                    \
    a0 = *(const bf16x8*)&Ap_[(wr*128 + ((mh)*4+0)*16 + lo16)*32 + fco];      \
    a1 = *(const bf16x8*)&Ap_[(wr*128 + ((mh)*4+1)*16 + lo16)*32 + fco];      \
    a2 = *(const bf16x8*)&Ap_[(wr*128 + ((mh)*4+2)*16 + lo16)*32 + fco];      \
    a3 = *(const bf16x8*)&Ap_[(wr*128 + ((mh)*4+3)*16 + lo16)*32 + fco];      \
    if ((mh) == 0) {                                                          \
        bfr0 = *(const bf16x8*)&Bp_[(wc*64 + 0*16 + lo16)*32 + fco];          \
        bfr1 = *(const bf16x8*)&Bp_[(wc*64 + 1*16 + lo16)*32 + fco];          \
        bfr2 = *(const bf16x8*)&Bp_[(wc*64 + 2*16 + lo16)*32 + fco];          \
        bfr3 = *(const bf16x8*)&Bp_[(wc*64 + 3*16 + lo16)*32 + fco];          \
    }                                                                         \
    STAGESTMT;                                                                \
    SBAR;                                                                     \
    __builtin_amdgcn_s_setprio(1);                                            \
    acc[(mh)*4+0][0] = __builtin_amdgcn_mfma_f32_16x16x32_bf16(a0, bfr0, acc[(mh)*4+0][0], 0,0,0); \
    acc[(mh)*4+0][1] = __builtin_amdgcn_mfma_f32_16x16x32_bf16(a0, bfr1, acc[(mh)*4+0][1], 0,0,0); \
    acc[(mh)*4+0][2] = __builtin_amdgcn_mfma_f32_16x16x32_bf16(a0, bfr2, acc[(mh)*4+0][2], 0,0,0); \
    acc[(mh)*4+0][3] = __builtin_amdgcn_mfma_f32_16x16x32_bf16(a0, bfr3, acc[(mh)*4+0][3], 0,0,0); \
    acc[(mh)*4+1][0] = __builtin_amdgcn_mfma_f32_16x16x32_bf16(a1, bfr0, acc[(mh)*4+1][0], 0,0,0); \
    acc[(mh)*4+1][1] = __builtin_amdgcn_mfma_f32_16x16x32_bf16(a1, bfr1, acc[(mh)*4+1][1], 0,0,0); \
    acc[(mh)*4+1][2] = __builtin_amdgcn_mfma_f32_16x16x32_bf16(a1, bfr2, acc[(mh)*4+1][2], 0,0,0); \
    acc[(mh)*4+1][3] = __builtin_amdgcn_mfma_f32_16x16x32_bf16(a1, bfr3, acc[(mh)*4+1][3], 0,0,0); \
    acc[(mh)*4+2][0] = __builtin_amdgcn_mfma_f32_16x16x32_bf16(a2, bfr0, acc[(mh)*4+2][0], 0,0,0); \
    acc[(mh)*4+2][1] = __builtin_amdgcn_mfma_f32_16x16x32_bf16(a2, bfr1, acc[(mh)*4+2][1], 0,0,0); \
    acc[(mh)*4+2][2] = __builtin_amdgcn_mfma_f32_16x16x32_bf16(a2, bfr2, acc[(mh)*4+2][2], 0,0,0); \
    acc[(mh)*4+2][3] = __builtin_amdgcn_mfma_f32_16x16x32_bf16(a2, bfr3, acc[(mh)*4+2][3], 0,0,0); \
    acc[(mh)*4+3][0] = __builtin_amdgcn_mfma_f32_16x16x32_bf16(a3, bfr0, acc[(mh)*4+3][0], 0,0,0); \
    acc[(mh)*4+3][1] = __builtin_amdgcn_mfma_f32_16x16x32_bf16(a3, bfr1, acc[(mh)*4+3][1], 0,0,0); \
    acc[(mh)*4+3][2] = __builtin_amdgcn_mfma_f32_16x16x32_bf16(a3, bfr2, acc[(mh)*4+3][2], 0,0,0); \
    acc[(mh)*4+3][3] = __builtin_amdgcn_mfma_f32_16x16x32_bf16(a3, bfr3, acc[(mh)*4+3][3], 0,0,0); \
    __builtin_amdgcn_s_setprio(0);                                            \
    VMSTMT;                                                                   \
    SBAR;                                                                     \
} while (0)

#define TILE(t, SA0, SB0, SA1, SB1, V2, V4)                                   \
    PH(t, 0, 0, SA0, NOPS);                                                   \
    PH(t, 1, 0, SB0, V2);                                                     \
    PH(t, 0, 1, SA1, NOPS);                                                   \
    PH(t, 1, 1, SB1, V4)

    // prologue: stage tile 0 fully; wait its kk0 (leave kk1's 4); barrier
    STAGE(0, 0, 0); STAGE(0, 1, 0); STAGE(0, 0, 1); STAGE(0, 1, 1);
    VM4;
    SBAR;

#pragma unroll 2
    for (int t = 0; t <= 22; ++t) {
        TILE(t, STAGE(t + 1, 0, 0), STAGE(t + 1, 1, 0),
                STAGE(t + 1, 0, 1), STAGE(t + 1, 1, 1), VM4, VM4);
    }
    TILE(23, NOPS, NOPS, NOPS, NOPS, VM0, NOPS);

#undef TILE
#undef PH
#undef STAGE

    // epilogue: fused argmin. col = brow + wc*64 + n*16 + lo16
    int coln[4]; float cnv[4];
#pragma unroll
    for (int n = 0; n < 4; ++n) {
        coln[n] = brow + wc * 64 + n * 16 + lo16;
        cnv[n] = cnorm[coln[n]];
    }
#pragma unroll
    for (int m = 0; m < 8; ++m) {
#pragma unroll
        for (int j = 0; j < 4; ++j) {
            unsigned long long best = 0xFFFFFFFFFFFFFFFFull;
#pragma unroll
            for (int n = 0; n < 4; ++n) {
                float d = fmaf(-2.0f, acc[m][n][j], cnv[n]);
                unsigned u = __float_as_uint(d);
                u = (u & 0x80000000u) ? ~u : (u | 0x80000000u);   // order-preserving map
                unsigned long long pk = ((unsigned long long)u << 32) | (unsigned)coln[n];
                best = pk < best ? pk : best;
            }
#pragma unroll
            for (int mask = 1; mask <= 8; mask <<= 1) {
                unsigned long long o = __shfl_xor(best, mask, 64);
                best = o < best ? o : best;
            }
            if (lo16 == 0) {
                const int row = arow + wr * 128 + m * 16 + hi4 * 4 + j;
                atomicMin(&packed[row], best);
            }
        }
    }
}

// ---------------------------------------------------------------------------
// gather (packed): z_q write, out_idx write, vq_loss accumulate
// ---------------------------------------------------------------------------
__global__ __launch_bounds__(256, 2)
void vq_gather_packed_kernel(const float* __restrict__ cb, const float* __restrict__ z,
                             const unsigned long long* __restrict__ packed,
                             float* __restrict__ out_zq, float* __restrict__ out_idx,
                             float* __restrict__ loss)
{
    __shared__ float rows[64 * 257];
    __shared__ int   ks[64];
    __shared__ float wsum[4];

    const int t   = threadIdx.x;
    const int blk = blockIdx.x;            // 512 blocks
    const int b   = blk >> 4;
    const int hw0 = (blk & 15) << 6;
    const int n0  = blk << 6;

    if (t < 64) {
        const int k = (int)(packed[n0 + t] & 0xFFFFFFFFull);
        ks[t] = k;
        out_idx[n0 + t] = (float)k;
    }
    __syncthreads();

#pragma unroll 4
    for (int i = 0; i < 64; ++i) {
        rows[i * 257 + t] = cb[(size_t)ks[i] * 256 + t];
    }
    __syncthreads();

    const int dq = t >> 6;
    const int hw = t & 63;
    const size_t obase = ((size_t)b << 18) + hw0 + hw;
    float sum = 0.f;
#pragma unroll 4
    for (int dd = 0; dd < 64; ++dd) {
        const int d = (dq << 6) + dd;
        const float  q  = rows[hw * 257 + d];
        const size_t a  = obase + (size_t)d * 1024;
        const float  zv = z[a];
        out_zq[a] = q;
        const float diff = q - zv;
        sum = fmaf(diff, diff, sum);
    }
#pragma unroll
    for (int m = 1; m <= 32; m <<= 1) sum += __shfl_xor(sum, m, 64);
    if ((t & 63) == 0) wsum[t >> 6] = sum;
    __syncthreads();
    if (t == 0) {
        const float s = (wsum[0] + wsum[1]) + (wsum[2] + wsum[3]);
        atomicAdd(loss, s * (1.25f / 8388608.0f));   // (1+0.25)*SSE/(B*D*H*W)
    }
}

// ===========================================================================
// FALLBACK PATH (ws too small): round-3 fp32 VALU kernels, known-passing.
// ===========================================================================
__global__ __launch_bounds__(256)
void vq_transpose_kernel(const float* __restrict__ cb, float* __restrict__ ctT)
{
    __shared__ float tile[64 * 65];
    const int t  = threadIdx.x;
    const int kb = blockIdx.x >> 2, db = blockIdx.x & 3;
    const int k0 = kb << 6, d0 = db << 6;
#pragma unroll
    for (int i = 0; i < 16; ++i) {
        int idx = i * 256 + t;
        int r = idx >> 6, c = idx & 63;
        tile[r * 65 + c] = cb[(size_t)(k0 + r) * 256 + d0 + c];
    }
    __syncthreads();
#pragma unroll
    for (int i = 0; i < 16; ++i) {
        int idx = i * 256 + t;
        int r = idx >> 6, c = idx & 63;
        ctT[(size_t)(d0 + r) * 1024 + k0 + c] = tile[c * 65 + r];
    }
}

__global__ __launch_bounds__(256)
void vq_cnorm_fb_kernel(const float* __restrict__ cb, float* __restrict__ cnorm)
{
    const int k = blockIdx.x * 256 + threadIdx.x;  // grid=4
    const float4* row = reinterpret_cast<const float4*>(cb + (size_t)k * 256);
    float s0 = 0.f, s1 = 0.f, s2 = 0.f, s3 = 0.f;
#pragma unroll 8
    for (int i = 0; i < 64; ++i) {
        float4 v = row[i];
        s0 = fmaf(v.x, v.x, s0);
        s1 = fmaf(v.y, v.y, s1);
        s2 = fmaf(v.z, v.z, s2);
        s3 = fmaf(v.w, v.w, s3);
    }
    cnorm[k] = (s0 + s1) + (s2 + s3);
}

__global__ __launch_bounds__(512, 2)
void vq_argmin_kernel(const float* __restrict__ z, const float* __restrict__ ctT,
                      const float* __restrict__ cnorm, int* __restrict__ codes,
                      float* __restrict__ out_idx)
{
    __shared__ float zt[256 * 64];
    __shared__ float ct[16 * 256];
    const int t = threadIdx.x, tx = t & 63, ty = t >> 6, p0 = ty << 3;
    const int blk = blockIdx.x, b = blk >> 4, hw0 = (blk & 15) << 6;
    const float* zbase = z + ((size_t)b << 18) + hw0;
#pragma unroll
    for (int i = 0; i < 8; ++i) {
        int idx = i * 512 + t;
        int d = idx >> 4, c4 = (idx & 15) << 2;
        float4 v = *reinterpret_cast<const float4*>(zbase + (size_t)d * 1024 + c4);
        *reinterpret_cast<float4*>(&zt[d * 64 + c4]) = v;
    }
    float minv[8]; int mini[8];
#pragma unroll
    for (int i = 0; i < 8; ++i) { minv[i] = 3.0e38f; mini[i] = 0; }
    const float* zrd = &zt[p0];
    const float* crd = &ct[tx << 2];
    for (int kt = 0; kt < 4; ++kt) {
        const int k0 = kt << 8;
        float acc[8][4];
#pragma unroll
        for (int i = 0; i < 8; ++i)
#pragma unroll
            for (int j = 0; j < 4; ++j) acc[i][j] = 0.f;
        for (int dc = 0; dc < 16; ++dc) {
            const int d0 = dc << 4;
            __syncthreads();
#pragma unroll
            for (int i = 0; i < 2; ++i) {
                int idx = i * 512 + t;
                int r = idx >> 6, c4 = (idx & 63) << 2;
                float4 v = *reinterpret_cast<const float4*>(ctT + (size_t)(d0 + r) * 1024 + k0 + c4);
                *reinterpret_cast<float4*>(&ct[r * 256 + c4]) = v;
            }
            __syncthreads();
            const float* zp = zrd + d0 * 64;
#pragma unroll
            for (int d = 0; d < 16; ++d) {
                float4 za = *reinterpret_cast<const float4*>(zp + d * 64);
                float4 zb = *reinterpret_cast<const float4*>(zp + d * 64 + 4);
                float4 cc = *reinterpret_cast<const float4*>(crd + d * 256);
#define VQ_FMA_ROW(ii, zv)                          \
                acc[ii][0] = fmaf(zv, cc.x, acc[ii][0]); \
                acc[ii][1] = fmaf(zv, cc.y, acc[ii][1]); \
                acc[ii][2] = fmaf(zv, cc.z, acc[ii][2]); \
                acc[ii][3] = fmaf(zv, cc.w, acc[ii][3]);
                VQ_FMA_ROW(0, za.x) VQ_FMA_ROW(1, za.y) VQ_FMA_ROW(2, za.z) VQ_FMA_ROW(3, za.w)
                VQ_FMA_ROW(4, zb.x) VQ_FMA_ROW(5, zb.y) VQ_FMA_ROW(6, zb.z) VQ_FMA_ROW(7, zb.w)
#undef VQ_FMA_ROW
            }
        }
#pragma unroll
        for (int j = 0; j < 4; ++j) {
            const int k = k0 + (tx << 2) + j;
            const float cn = cnorm[k];
#pragma unroll
            for (int i = 0; i < 8; ++i) {
                float dist = fmaf(-2.0f, acc[i][j], cn);
                if (dist < minv[i]) { minv[i] = dist; mini[i] = k; }
            }
        }
    }
#pragma unroll
    for (int m = 1; m <= 32; m <<= 1) {
#pragma unroll
        for (int i = 0; i < 8; ++i) {
            float ov = __shfl_xor(minv[i], m, 64);
            int   oi = __shfl_xor(mini[i], m, 64);
            if (ov < minv[i] || (ov == minv[i] && oi < mini[i])) { minv[i] = ov; mini[i] = oi; }
        }
    }
    if (tx == 0) {
        const int n0 = (blk << 6) + p0;
#pragma unroll
        for (int i = 0; i < 8; ++i) {
            codes[n0 + i]   = mini[i];
            out_idx[n0 + i] = (float)mini[i];
        }
    }
}

__global__ __launch_bounds__(256, 2)
void vq_gather_kernel(const float* __restrict__ cb, const float* __restrict__ z,
                      const int* __restrict__ codes, float* __restrict__ out_zq,
                      float* __restrict__ loss)
{
    __shared__ float rows[64 * 257];
    __shared__ int   ks[64];
    __shared__ float wsum[4];
    const int t = threadIdx.x, blk = blockIdx.x;
    const int b = blk >> 4, hw0 = (blk & 15) << 6, n0 = blk << 6;
    if (t < 64) ks[t] = codes[n0 + t];
    __syncthreads();
#pragma unroll 4
    for (int i = 0; i < 64; ++i) rows[i * 257 + t] = cb[(size_t)ks[i] * 256 + t];
    __syncthreads();
    const int dq = t >> 6, hw = t & 63;
    const size_t obase = ((size_t)b << 18) + hw0 + hw;
    float sum = 0.f;
#pragma unroll 4
    for (int dd = 0; dd < 64; ++dd) {
        const int d = (dq << 6) + dd;
        const float  q  = rows[hw * 257 + d];
        const size_t a  = obase + (size_t)d * 1024;
        const float  zv = z[a];
        out_zq[a] = q;
        const float diff = q - zv;
        sum = fmaf(diff, diff, sum);
    }
#pragma unroll
    for (int m = 1; m <= 32; m <<= 1) sum += __shfl_xor(sum, m, 64);
    if ((t & 63) == 0) wsum[t >> 6] = sum;
    __syncthreads();
    if (t == 0) {
        const float s = (wsum[0] + wsum[1]) + (wsum[2] + wsum[3]);
        atomicAdd(loss, s * (1.25f / 8388608.0f));
    }
}

// ---------------------------------------------------------------------------
extern "C" void kernel_launch(void* const* d_in, const int* in_sizes, int n_in,
                              void* d_out, int out_size, void* d_ws, size_t ws_size,
                              hipStream_t stream)
{
    (void)in_sizes; (void)n_in; (void)out_size;

    const float* z  = (const float*)d_in[0];   // 32*256*32*32 fp32
    const float* cb = (const float*)d_in[1];   // 1024*256 fp32

    float* out      = (float*)d_out;
    float* out_zq   = out;                     // 8388608
    float* out_idx  = out + 8388608;           // 32768 (indices as float values)
    float* out_loss = out + 8421376;           // 1

    // MFMA-path workspace: packed(256KB) | z0|z1|z2 (16MB each) | c0|c1|c2 | cnorm
    const size_t NEED = 262144ull + 3ull * 16777216ull + 3ull * 524288ull + 4096ull;

    if (ws_size >= NEED) {
        unsigned long long* packed = (unsigned long long*)d_ws;
        unsigned short* z0 = (unsigned short*)((char*)d_ws + 262144);
        unsigned short* z1 = z0 + 8388608u;
        unsigned short* z2 = z1 + 8388608u;
        unsigned short* c0 = z2 + 8388608u;
        unsigned short* c1 = c0 + 262144u;
        unsigned short* c2 = c1 + 262144u;
        float* cnorm = (float*)(c2 + 262144u);

        vq_csplit_kernel<<<256, 256, 0, stream>>>(cb, c0, c1, c2, packed, out_loss);
        vq_cnorm_kernel<<<4, 256, 0, stream>>>(cb, cnorm);
        vq_zsplit_kernel<<<512, 256, 0, stream>>>(z, z0, z1, z2);
        vq_mfma_argmin_kernel<<<512, 512, 0, stream>>>(z0, c0, cnorm, packed);
        vq_gather_packed_kernel<<<512, 256, 0, stream>>>(cb, z, packed, out_zq, out_idx, out_loss);
    } else {
        // fallback: round-3 fp32 path (ws >= 1.38MB known OK)
        float* ctT   = (float*)d_ws;
        float* cnorm = ctT + 256 * 1024;
        int*   codes = (int*)(cnorm + 1024);

        hipMemsetAsync(out_loss, 0, sizeof(float), stream);
        vq_transpose_kernel<<<64, 256, 0, stream>>>(cb, ctT);
        vq_cnorm_fb_kernel<<<4, 256, 0, stream>>>(cb, cnorm);
        vq_argmin_kernel<<<512, 512, 0, stream>>>(z, ctT, cnorm, codes, out_idx);
        vq_gather_kernel<<<512, 256, 0, stream>>>(cb, z, codes, out_zq, out_loss);
    }
}

// Round 16
// 155.108 us; speedup vs baseline: 1.1223x; 1.1223x over previous
//
#include <hip/hip_runtime.h>
#include <cstdint>
#include <cstddef>

// Problem constants (B=32, D=256, H=32, W=32, K=1024), N = B*H*W = 32768.
// MFMA path: fp32 -> 3x bf16 split; 6 concat-K segments -> bf16 GEMM
// M=32768 N=1024 K=1536; error ~ fp32 accumulation (numpy-grade).
//
// This file is the ROUND-9 TRANSLATION UNIT, byte-for-byte (measured:
// total 156.17µs, GEMM 114.9µs, MfmaUtil 38%, VGPR 124, FETCH 37MB,
// WRITE 16KB, 0 bank conflicts). r15's "restore" differed in the GEMM
// prologue/loop (r12's 1-tile-deep prefetch instead of r9's 2-tile VM12/
// VM8 prologue + t=1..22 loop) and spilled (VGPR 128, FETCH 107MB).
// The kernel sits at 124 VGPR + 128 AGPR = 252/256 regs: the loop
// structure is part of the configuration. Do not modify piecewise —
// r10-r14 documented that every local perturbation (fat phase, barrier
// cut, smaller wave tiles, X/Y frag dbuf) spills or loses to this config.

typedef __attribute__((ext_vector_type(8))) short bf16x8;
typedef __attribute__((ext_vector_type(4))) float f32x4;

#define GL2LDS(g, l) __builtin_amdgcn_global_load_lds( \
    (__attribute__((address_space(1))) const void*)(g), \
    (__attribute__((address_space(3))) void*)(l), 16, 0, 0)

__device__ __forceinline__ unsigned short rne_bf16(float f) {
    unsigned u = __float_as_uint(f);
    return (unsigned short)((u + 0x7FFFu + ((u >> 16) & 1u)) >> 16);
}
__device__ __forceinline__ float bf16_to_f(unsigned short h) {
    return __uint_as_float((unsigned)h << 16);
}

// ---------------------------------------------------------------------------
// codebook row norms ||c_k||^2
// ---------------------------------------------------------------------------
__global__ __launch_bounds__(256)
void vq_cnorm_kernel(const float* __restrict__ cb, float* __restrict__ cnorm)
{
    const int k = blockIdx.x * 256 + threadIdx.x;  // grid=4
    const float4* row = reinterpret_cast<const float4*>(cb + (size_t)k * 256);
    float s0 = 0.f, s1 = 0.f, s2 = 0.f, s3 = 0.f;
#pragma unroll 8
    for (int i = 0; i < 64; ++i) {
        float4 v = row[i];
        s0 = fmaf(v.x, v.x, s0);
        s1 = fmaf(v.y, v.y, s1);
        s2 = fmaf(v.z, v.z, s2);
        s3 = fmaf(v.w, v.w, s3);
    }
    cnorm[k] = (s0 + s1) + (s2 + s3);
}

// ---------------------------------------------------------------------------
// codebook split: [1024][256] fp32 -> c0,c1,c2 bf16
// ---------------------------------------------------------------------------
__global__ __launch_bounds__(256)
void vq_csplit_kernel(const float* __restrict__ cb, unsigned short* __restrict__ c0,
                      unsigned short* __restrict__ c1, unsigned short* __restrict__ c2)
{
    const int idx = blockIdx.x * 256 + threadIdx.x;   // grid 256
    float4 v = reinterpret_cast<const float4*>(cb)[idx];
    float f[4] = { v.x, v.y, v.z, v.w };
    ushort4 h0, h1, h2;
    unsigned short* p0[4] = { &h0.x, &h0.y, &h0.z, &h0.w };
    unsigned short* p1[4] = { &h1.x, &h1.y, &h1.z, &h1.w };
    unsigned short* p2[4] = { &h2.x, &h2.y, &h2.z, &h2.w };
#pragma unroll
    for (int j = 0; j < 4; ++j) {
        unsigned short b0 = rne_bf16(f[j]); float r1 = f[j] - bf16_to_f(b0);
        unsigned short b1 = rne_bf16(r1);   float r2 = r1 - bf16_to_f(b1);
        unsigned short b2 = rne_bf16(r2);
        *p0[j] = b0; *p1[j] = b1; *p2[j] = b2;
    }
    reinterpret_cast<ushort4*>(c0)[idx] = h0;
    reinterpret_cast<ushort4*>(c1)[idx] = h1;
    reinterpret_cast<ushort4*>(c2)[idx] = h2;
}

// ---------------------------------------------------------------------------
// z split+transpose: z[b][d][hw] fp32 -> z0,z1,z2 bf16 [n][d]
// ---------------------------------------------------------------------------
__global__ __launch_bounds__(256)
void vq_zsplit_kernel(const float* __restrict__ z, unsigned short* __restrict__ z0,
                      unsigned short* __restrict__ z1, unsigned short* __restrict__ z2)
{
    __shared__ float zl[64 * 264];
    const int t = threadIdx.x, blk = blockIdx.x;        // 512 blocks
    const int b = blk >> 4, hw0 = (blk & 15) << 6;
    const float* zb = z + ((size_t)b << 18) + hw0;
#pragma unroll 8
    for (int i = 0; i < 64; ++i) {
        int idx = i * 256 + t;
        int d = idx >> 6, hwl = idx & 63;
        zl[hwl * 264 + d] = zb[(size_t)d * 1024 + hwl];
    }
    __syncthreads();
    const int n0 = (b << 10) + hw0;
#pragma unroll
    for (int p = 0; p < 8; ++p) {
        const int hwl = p * 8 + (t >> 5);
        const int d0 = (t & 31) * 8;
        const float* src = &zl[hwl * 264 + d0];
        unsigned short h0[8], h1[8], h2[8];
#pragma unroll
        for (int j = 0; j < 8; ++j) {
            float f = src[j];
            unsigned short b0 = rne_bf16(f);  float r1 = f - bf16_to_f(b0);
            unsigned short b1 = rne_bf16(r1); float r2 = r1 - bf16_to_f(b1);
            unsigned short b2 = rne_bf16(r2);
            h0[j] = b0; h1[j] = b1; h2[j] = b2;
        }
        const size_t o = (size_t)(n0 + hwl) * 256 + d0;
        ushort4 a;
        a = ushort4{h0[0],h0[1],h0[2],h0[3]}; *reinterpret_cast<ushort4*>(z0 + o)     = a;
        a = ushort4{h0[4],h0[5],h0[6],h0[7]}; *reinterpret_cast<ushort4*>(z0 + o + 4) = a;
        a = ushort4{h1[0],h1[1],h1[2],h1[3]}; *reinterpret_cast<ushort4*>(z1 + o)     = a;
        a = ushort4{h1[4],h1[5],h1[6],h1[7]}; *reinterpret_cast<ushort4*>(z1 + o + 4) = a;
        a = ushort4{h2[0],h2[1],h2[2],h2[3]}; *reinterpret_cast<ushort4*>(z2 + o)     = a;
        a = ushort4{h2[4],h2[5],h2[6],h2[7]}; *reinterpret_cast<ushort4*>(z2 + o + 4) = a;
    }
}

// ---------------------------------------------------------------------------
// MFMA GEMM + fused argmin — 256² tile, 8 waves, 4-phase/K-tile, counted vmcnt.
//
// LDS: Ld[buf2][mat2][kk2][256x32] bf16 = 128KB (1 block/CU, 8 waves).
// K-tile t lives in buf[t&1]; during tile t's phases, stage tile t+1's 4
// K-half planes into buf[(t+1)&1]. Counted waits: vmcnt(4)/(8) -- never 0
// until the tail (T4). Raw s_barrier + fences.
//
// Swizzle (both-sides, rule #21): plane row = 32 bf16 = 64B = 4 chunks;
// bank = (row&1)*16 + slot*4. Store chunk c of row r at slot c ^ ((r>>1)&3)
// (bits 1-2; bit 0 already moves the bank half). gl2lds writes linearly ->
// GLOBAL source chunk pre-swizzled: selem = ((l&3)^((l>>3)&3))*8 (row=l>>2).
// Read: fco = (hi4 ^ ((lo16>>1)&3))*8 (row ≡ lo16 mod 16). Audit: 16-lane
// phase covers all 8 (parity,slot) bank groups exactly 2x = b128 floor.
// Accumulation order unchanged -> bit-identical distances.
// ---------------------------------------------------------------------------
__global__ __launch_bounds__(512, 2)
void vq_mfma_argmin_kernel(const unsigned short* __restrict__ zp,
                           const unsigned short* __restrict__ cp,
                           const float* __restrict__ cnorm,
                           unsigned long long* __restrict__ packed)
{
    __shared__ unsigned short Ld[2][2][2][256 * 32];   // 128KB

    const int tid = threadIdx.x, l = tid & 63, w = tid >> 6;
    const int wr = w >> 2, wc = w & 3;                 // 2 x 4 wave grid
    const int nid = ((blockIdx.x & 7) << 6) | (blockIdx.x >> 3);  // XCD swizzle (512%8==0)
    const int bm = nid >> 2, bn = nid & 3;             // 128 x 4 tiles
    const int arow = bm * 256, brow = bn * 256;

    f32x4 acc[8][4];
#pragma unroll
    for (int m = 0; m < 8; ++m)
#pragma unroll
        for (int n = 0; n < 4; ++n) acc[m][n] = f32x4{0.f, 0.f, 0.f, 0.f};

    // staging lane geometry: lane l -> row l>>2, slot l&3; source chunk
    // pre-swizzled by row bits 1-2 ((l>>3)&3) so stored slot = c ^ ((r>>1)&3)
    const int srow  = l >> 2;
    const int selem = (((l & 3) ^ ((l >> 3) & 3))) << 3;

    // fragment-read: chunk hi4 of row r at slot hi4 ^ ((r>>1)&3); r ≡ lo16 (16)
    const int lo16 = l & 15, hi4 = l >> 4;
    const int fco = ((hi4 ^ ((lo16 >> 1) & 3))) << 3;

    // segment tables packed as nibbles: A {0,1,2,0,1,0}, B {0,0,0,1,1,2}
#define STAGE(tt, mat, kk) do {                                               \
    const int seg_ = (tt) >> 2;                                               \
    const unsigned short* S_ = (mat)                                          \
        ? cp + (size_t)((0x211000 >> (seg_ << 2)) & 3) * 262144u              \
        : zp + (size_t)((0x010210 >> (seg_ << 2)) & 3) * 8388608u;            \
    const int R_  = (mat) ? brow : arow;                                      \
    const int KO_ = (((tt) & 3) << 6) + ((kk) << 5) + selem;                  \
    GL2LDS(S_ + (size_t)(R_ + (w * 2 + 0) * 16 + srow) * 256 + KO_,           \
           &Ld[(tt) & 1][mat][kk][(w * 2 + 0) * 512]);                        \
    GL2LDS(S_ + (size_t)(R_ + (w * 2 + 1) * 16 + srow) * 256 + KO_,           \
           &Ld[(tt) & 1][mat][kk][(w * 2 + 1) * 512]);                        \
} while (0)

#define VM12 asm volatile("s_waitcnt vmcnt(12)" ::: "memory")
#define VM8  asm volatile("s_waitcnt vmcnt(8)"  ::: "memory")
#define VM4  asm volatile("s_waitcnt vmcnt(4)"  ::: "memory")
#define VM0  asm volatile("s_waitcnt vmcnt(0)"  ::: "memory")
#define NOPS ((void)0)
#define SBAR do { asm volatile("" ::: "memory");                              \
                  __builtin_amdgcn_s_barrier();                               \
                  __builtin_amdgcn_sched_barrier(0); } while (0)

    bf16x8 bfr0, bfr1, bfr2, bfr3;   // B frags, loaded at mh==0, reused mh==1

#define PH(t, mh, kk, STAGESTMT, VMSTMT) do {                                 \
    const unsigned short* Ap_ = &Ld[(t) & 1][0][kk][0];                       \
    const unsigned short* Bp_ = &Ld[(t) & 1][1][kk][0];                       \
    bf16x8 a0, a1, a2, a3;                                                    \
    a0 = *(const bf16x8*)&Ap_[(wr*128 + ((mh)*4+0)*16 + lo16)*32 + fco];      \
    a1 = *(const bf16x8*)&Ap_[(wr*128 + ((mh)*4+1)*16 + lo16)*32 + fco];      \
    a2 = *(const bf16x8*)&Ap_[(wr*128 + ((mh)*4+2)*16 + lo16)*32 + fco];      \
    a3 = *(const bf16x8*)&Ap_[(wr*128 + ((mh)*4+3)*16 + lo16)*32 + fco];      \
    if ((mh) == 0) {                                                          \
        bfr0 = *(const bf16x8*)&Bp_[(wc*64 + 0*16 + lo16)*32 + fco];          \
        bfr1 = *(const bf16x8*)&Bp_[(wc*64 + 1*16 + lo16)*32 + fco];          \
        bfr2 = *(const bf16x8*)&Bp_[(wc*64 + 2*16 + lo16)*32 + fco];          \
        bfr3 = *(const bf16x8*)&Bp_[(wc*64 + 3*16 + lo16)*32 + fco];          \
    }                                                                         \
    STAGESTMT;                                                                \
    SBAR;                                                                     \
    __builtin_amdgcn_s_setprio(1);                                            \
    acc[(mh)*4+0][0] = __builtin_amdgcn_mfma_f32_16x16x32_bf16(a0, bfr0, acc[(mh)*4+0][0], 0,0,0); \
    acc[(mh)*4+0][1] = __builtin_amdgcn_mfma_f32_16x16x32_bf16(a0, bfr1, acc[(mh)*4+0][1], 0,0,0); \
    acc[(mh)*4+0][2] = __builtin_amdgcn_mfma_f32_16x16x32_bf16(a0, bfr2, acc[(mh)*4+0][2], 0,0,0); \
    acc[(mh)*4+0][3] = __builtin_amdgcn_mfma_f32_16x16x32_bf16(a0, bfr3, acc[(mh)*4+0][3], 0,0,0); \
    acc[(mh)*4+1][0] = __builtin_amdgcn_mfma_f32_16x16x32_bf16(a1, bfr0, acc[(mh)*4+1][0], 0,0,0); \
    acc[(mh)*4+1][1] = __builtin_amdgcn_mfma_f32_16x16x32_bf16(a1, bfr1, acc[(mh)*4+1][1], 0,0,0); \
    acc[(mh)*4+1][2] = __builtin_amdgcn_mfma_f32_16x16x32_bf16(a1, bfr2, acc[(mh)*4+1][2], 0,0,0); \
    acc[(mh)*4+1][3] = __builtin_amdgcn_mfma_f32_16x16x32_bf16(a1, bfr3, acc[(mh)*4+1][3], 0,0,0); \
    acc[(mh)*4+2][0] = __builtin_amdgcn_mfma_f32_16x16x32_bf16(a2, bfr0, acc[(mh)*4+2][0], 0,0,0); \
    acc[(mh)*4+2][1] = __builtin_amdgcn_mfma_f32_16x16x32_bf16(a2, bfr1, acc[(mh)*4+2][1], 0,0,0); \
    acc[(mh)*4+2][2] = __builtin_amdgcn_mfma_f32_16x16x32_bf16(a2, bfr2, acc[(mh)*4+2][2], 0,0,0); \
    acc[(mh)*4+2][3] = __builtin_amdgcn_mfma_f32_16x16x32_bf16(a2, bfr3, acc[(mh)*4+2][3], 0,0,0); \
    acc[(mh)*4+3][0] = __builtin_amdgcn_mfma_f32_16x16x32_bf16(a3, bfr0, acc[(mh)*4+3][0], 0,0,0); \
    acc[(mh)*4+3][1] = __builtin_amdgcn_mfma_f32_16x16x32_bf16(a3, bfr1, acc[(mh)*4+3][1], 0,0,0); \
    acc[(mh)*4+3][2] = __builtin_amdgcn_mfma_f32_16x16x32_bf16(a3, bfr2, acc[(mh)*4+3][2], 0,0,0); \
    acc[(mh)*4+3][3] = __builtin_amdgcn_mfma_f32_16x16x32_bf16(a3, bfr3, acc[(mh)*4+3][3], 0,0,0); \
    __builtin_amdgcn_s_setprio(0);                                            \
    VMSTMT;                                                                   \
    SBAR;                                                                     \
} while (0)

#define TILE(t, SA0, SB0, SA1, SB1, V2, V4)                                   \
    PH(t, 0, 0, SA0, NOPS);                                                   \
    PH(t, 1, 0, SB0, V2);                                                     \
    PH(t, 0, 1, SA1, NOPS);                                                   \
    PH(t, 1, 1, SB1, V4)

    // prologue: stage tiles 0 and 1 (kh0 before kh1); wait tile0-kh0 only
    STAGE(0, 0, 0); STAGE(0, 1, 0); STAGE(0, 0, 1); STAGE(0, 1, 1);
    STAGE(1, 0, 0); STAGE(1, 1, 0); STAGE(1, 0, 1); STAGE(1, 1, 1);
    VM12;
    SBAR;

    TILE(0, NOPS, NOPS, NOPS, NOPS, VM8, VM4);
#pragma unroll 2
    for (int t = 1; t <= 22; ++t) {
        TILE(t, STAGE(t + 1, 0, 0), STAGE(t + 1, 1, 0),
                STAGE(t + 1, 0, 1), STAGE(t + 1, 1, 1), VM4, VM4);
    }
    TILE(23, NOPS, NOPS, NOPS, NOPS, VM0, NOPS);

#undef TILE
#undef PH
#undef STAGE

    // epilogue: fused argmin. col = brow + wc*64 + n*16 + lo16
    int coln[4]; float cnv[4];
#pragma unroll
    for (int n = 0; n < 4; ++n) {
        coln[n] = brow + wc * 64 + n * 16 + lo16;
        cnv[n] = cnorm[coln[n]];
    }
#pragma unroll
    for (int m = 0; m < 8; ++m) {
#pragma unroll
        for (int j = 0; j < 4; ++j) {
            unsigned long long best = 0xFFFFFFFFFFFFFFFFull;
#pragma unroll
            for (int n = 0; n < 4; ++n) {
                float d = fmaf(-2.0f, acc[m][n][j], cnv[n]);
                unsigned u = __float_as_uint(d);
                u = (u & 0x80000000u) ? ~u : (u | 0x80000000u);   // order-preserving map
                unsigned long long pk = ((unsigned long long)u << 32) | (unsigned)coln[n];
                best = pk < best ? pk : best;
            }
#pragma unroll
            for (int mask = 1; mask <= 8; mask <<= 1) {
                unsigned long long o = __shfl_xor(best, mask, 64);
                best = o < best ? o : best;
            }
            if (lo16 == 0) {
                const int row = arow + wr * 128 + m * 16 + hi4 * 4 + j;
                atomicMin(&packed[row], best);
            }
        }
    }
}

// ---------------------------------------------------------------------------
// gather (packed): z_q write, out_idx write, vq_loss accumulate
// ---------------------------------------------------------------------------
__global__ __launch_bounds__(256, 2)
void vq_gather_packed_kernel(const float* __restrict__ cb, const float* __restrict__ z,
                             const unsigned long long* __restrict__ packed,
                             float* __restrict__ out_zq, float* __restrict__ out_idx,
                             float* __restrict__ loss)
{
    __shared__ float rows[64 * 257];
    __shared__ int   ks[64];
    __shared__ float wsum[4];

    const int t   = threadIdx.x;
    const int blk = blockIdx.x;            // 512 blocks
    const int b   = blk >> 4;
    const int hw0 = (blk & 15) << 6;
    const int n0  = blk << 6;

    if (t < 64) {
        const int k = (int)(packed[n0 + t] & 0xFFFFFFFFull);
        ks[t] = k;
        out_idx[n0 + t] = (float)k;
    }
    __syncthreads();

#pragma unroll 4
    for (int i = 0; i < 64; ++i) {
        rows[i * 257 + t] = cb[(size_t)ks[i] * 256 + t];
    }
    __syncthreads();

    const int dq = t >> 6;
    const int hw = t & 63;
    const size_t obase = ((size_t)b << 18) + hw0 + hw;
    float sum = 0.f;
#pragma unroll 4
    for (int dd = 0; dd < 64; ++dd) {
        const int d = (dq << 6) + dd;
        const float  q  = rows[hw * 257 + d];
        const size_t a  = obase + (size_t)d * 1024;
        const float  zv = z[a];
        out_zq[a] = q;
        const float diff = q - zv;
        sum = fmaf(diff, diff, sum);
    }
#pragma unroll
    for (int m = 1; m <= 32; m <<= 1) sum += __shfl_xor(sum, m, 64);
    if ((t & 63) == 0) wsum[t >> 6] = sum;
    __syncthreads();
    if (t == 0) {
        const float s = (wsum[0] + wsum[1]) + (wsum[2] + wsum[3]);
        atomicAdd(loss, s * (1.25f / 8388608.0f));   // (1+0.25)*SSE/(B*D*H*W)
    }
}

// ===========================================================================
// FALLBACK PATH (ws too small): round-3 fp32 VALU kernels, known-passing.
// ===========================================================================
__global__ __launch_bounds__(256)
void vq_transpose_kernel(const float* __restrict__ cb, float* __restrict__ ctT)
{
    __shared__ float tile[64 * 65];
    const int t  = threadIdx.x;
    const int kb = blockIdx.x >> 2, db = blockIdx.x & 3;
    const int k0 = kb << 6, d0 = db << 6;
#pragma unroll
    for (int i = 0; i < 16; ++i) {
        int idx = i * 256 + t;
        int r = idx >> 6, c = idx & 63;
        tile[r * 65 + c] = cb[(size_t)(k0 + r) * 256 + d0 + c];
    }
    __syncthreads();
#pragma unroll
    for (int i = 0; i < 16; ++i) {
        int idx = i * 256 + t;
        int r = idx >> 6, c = idx & 63;
        ctT[(size_t)(d0 + r) * 1024 + k0 + c] = tile[c * 65 + r];
    }
}

__global__ __launch_bounds__(512, 2)
void vq_argmin_kernel(const float* __restrict__ z, const float* __restrict__ ctT,
                      const float* __restrict__ cnorm, int* __restrict__ codes,
                      float* __restrict__ out_idx)
{
    __shared__ float zt[256 * 64];
    __shared__ float ct[16 * 256];
    const int t = threadIdx.x, tx = t & 63, ty = t >> 6, p0 = ty << 3;
    const int blk = blockIdx.x, b = blk >> 4, hw0 = (blk & 15) << 6;
    const float* zbase = z + ((size_t)b << 18) + hw0;
#pragma unroll
    for (int i = 0; i < 8; ++i) {
        int idx = i * 512 + t;
        int d = idx >> 4, c4 = (idx & 15) << 2;
        float4 v = *reinterpret_cast<const float4*>(zbase + (size_t)d * 1024 + c4);
        *reinterpret_cast<float4*>(&zt[d * 64 + c4]) = v;
    }
    float minv[8]; int mini[8];
#pragma unroll
    for (int i = 0; i < 8; ++i) { minv[i] = 3.0e38f; mini[i] = 0; }
    const float* zrd = &zt[p0];
    const float* crd = &ct[tx << 2];
    for (int kt = 0; kt < 4; ++kt) {
        const int k0 = kt << 8;
        float acc[8][4];
#pragma unroll
        for (int i = 0; i < 8; ++i)
#pragma unroll
            for (int j = 0; j < 4; ++j) acc[i][j] = 0.f;
        for (int dc = 0; dc < 16; ++dc) {
            const int d0 = dc << 4;
            __syncthreads();
#pragma unroll
            for (int i = 0; i < 2; ++i) {
                int idx = i * 512 + t;
                int r = idx >> 6, c4 = (idx & 63) << 2;
                float4 v = *reinterpret_cast<const float4*>(ctT + (size_t)(d0 + r) * 1024 + k0 + c4);
                *reinterpret_cast<float4*>(&ct[r * 256 + c4]) = v;
            }
            __syncthreads();
            const float* zp = zrd + d0 * 64;
#pragma unroll
            for (int d = 0; d < 16; ++d) {
                float4 za = *reinterpret_cast<const float4*>(zp + d * 64);
                float4 zb = *reinterpret_cast<const float4*>(zp + d * 64 + 4);
                float4 cc = *reinterpret_cast<const float4*>(crd + d * 256);
#define VQ_FMA_ROW(ii, zv)                          \
                acc[ii][0] = fmaf(zv, cc.x, acc[ii][0]); \
                acc[ii][1] = fmaf(zv, cc.y, acc[ii][1]); \
                acc[ii][2] = fmaf(zv, cc.z, acc[ii][2]); \
                acc[ii][3] = fmaf(zv, cc.w, acc[ii][3]);
                VQ_FMA_ROW(0, za.x) VQ_FMA_ROW(1, za.y) VQ_FMA_ROW(2, za.z) VQ_FMA_ROW(3, za.w)
                VQ_FMA_ROW(4, zb.x) VQ_FMA_ROW(5, zb.y) VQ_FMA_ROW(6, zb.z) VQ_FMA_ROW(7, zb.w)
#undef VQ_FMA_ROW
            }
        }
#pragma unroll
        for (int j = 0; j < 4; ++j) {
            const int k = k0 + (tx << 2) + j;
            const float cn = cnorm[k];
#pragma unroll
            for (int i = 0; i < 8; ++i) {
                float dist = fmaf(-2.0f, acc[i][j], cn);
                if (dist < minv[i]) { minv[i] = dist; mini[i] = k; }
            }
        }
    }
#pragma unroll
    for (int m = 1; m <= 32; m <<= 1) {
#pragma unroll
        for (int i = 0; i < 8; ++i) {
            float ov = __shfl_xor(minv[i], m, 64);
            int   oi = __shfl_xor(mini[i], m, 64);
            if (ov < minv[i] || (ov == minv[i] && oi < mini[i])) { minv[i] = ov; mini[i] = oi; }
        }
    }
    if (tx == 0) {
        const int n0 = (blk << 6) + p0;
#pragma unroll
        for (int i = 0; i < 8; ++i) {
            codes[n0 + i]   = mini[i];
            out_idx[n0 + i] = (float)mini[i];
        }
    }
}

__global__ __launch_bounds__(256, 2)
void vq_gather_kernel(const float* __restrict__ cb, const float* __restrict__ z,
                      const int* __restrict__ codes, float* __restrict__ out_zq,
                      float* __restrict__ loss)
{
    __shared__ float rows[64 * 257];
    __shared__ int   ks[64];
    __shared__ float wsum[4];
    const int t = threadIdx.x, blk = blockIdx.x;
    const int b = blk >> 4, hw0 = (blk & 15) << 6, n0 = blk << 6;
    if (t < 64) ks[t] = codes[n0 + t];
    __syncthreads();
#pragma unroll 4
    for (int i = 0; i < 64; ++i) rows[i * 257 + t] = cb[(size_t)ks[i] * 256 + t];
    __syncthreads();
    const int dq = t >> 6, hw = t & 63;
    const size_t obase = ((size_t)b << 18) + hw0 + hw;
    float sum = 0.f;
#pragma unroll 4
    for (int dd = 0; dd < 64; ++dd) {
        const int d = (dq << 6) + dd;
        const float  q  = rows[hw * 257 + d];
        const size_t a  = obase + (size_t)d * 1024;
        const float  zv = z[a];
        out_zq[a] = q;
        const float diff = q - zv;
        sum = fmaf(diff, diff, sum);
    }
#pragma unroll
    for (int m = 1; m <= 32; m <<= 1) sum += __shfl_xor(sum, m, 64);
    if ((t & 63) == 0) wsum[t >> 6] = sum;
    __syncthreads();
    if (t == 0) {
        const float s = (wsum[0] + wsum[1]) + (wsum[2] + wsum[3]);
        atomicAdd(loss, s * (1.25f / 8388608.0f));
    }
}

// ---------------------------------------------------------------------------
extern "C" void kernel_launch(void* const* d_in, const int* in_sizes, int n_in,
                              void* d_out, int out_size, void* d_ws, size_t ws_size,
                              hipStream_t stream)
{
    (void)in_sizes; (void)n_in; (void)out_size;

    const float* z  = (const float*)d_in[0];   // 32*256*32*32 fp32
    const float* cb = (const float*)d_in[1];   // 1024*256 fp32

    float* out      = (float*)d_out;
    float* out_zq   = out;                     // 8388608
    float* out_idx  = out + 8388608;           // 32768 (indices as float values)
    float* out_loss = out + 8421376;           // 1

    // MFMA-path workspace: packed(256KB) | z0|z1|z2 (16MB each) | c0|c1|c2 | cnorm
    const size_t NEED = 262144ull + 3ull * 16777216ull + 3ull * 524288ull + 4096ull;

    if (ws_size >= NEED) {
        unsigned long long* packed = (unsigned long long*)d_ws;
        unsigned short* z0 = (unsigned short*)((char*)d_ws + 262144);
        unsigned short* z1 = z0 + 8388608u;
        unsigned short* z2 = z1 + 8388608u;
        unsigned short* c0 = z2 + 8388608u;
        unsigned short* c1 = c0 + 262144u;
        unsigned short* c2 = c1 + 262144u;
        float* cnorm = (float*)(c2 + 262144u);

        hipMemsetAsync(out_loss, 0, sizeof(float), stream);
        hipMemsetAsync(packed, 0xFF, 262144, stream);
        vq_csplit_kernel<<<256, 256, 0, stream>>>(cb, c0, c1, c2);
        vq_cnorm_kernel<<<4, 256, 0, stream>>>(cb, cnorm);
        vq_zsplit_kernel<<<512, 256, 0, stream>>>(z, z0, z1, z2);
        vq_mfma_argmin_kernel<<<512, 512, 0, stream>>>(z0, c0, cnorm, packed);
        vq_gather_packed_kernel<<<512, 256, 0, stream>>>(cb, z, packed, out_zq, out_idx, out_loss);
    } else {
        // fallback: round-3 fp32 path (ws >= 1.38MB known OK)
        float* ctT   = (float*)d_ws;
        float* cnorm = ctT + 256 * 1024;
        int*   codes = (int*)(cnorm + 1024);

        hipMemsetAsync(out_loss, 0, sizeof(float), stream);
        vq_transpose_kernel<<<64, 256, 0, stream>>>(cb, ctT);
        vq_cnorm_kernel<<<4, 256, 0, stream>>>(cb, cnorm);
        vq_argmin_kernel<<<512, 512, 0, stream>>>(z, ctT, cnorm, codes, out_idx);
        vq_gather_kernel<<<512, 256, 0, stream>>>(cb, z, codes, out_zq, out_loss);
    }
}

// Round 17
// 151.593 us; speedup vs baseline: 1.1483x; 1.0232x over previous
//
#include <hip/hip_runtime.h>
#include <cstdint>
#include <cstddef>

// Problem constants (B=32, D=256, H=32, W=32, K=1024), N = B*H*W = 32768.
// MFMA path: fp32 -> 3x bf16 split; 6 concat-K segments -> bf16 GEMM
// M=32768 N=1024 K=1536; error ~ fp32 accumulation (numpy-grade).
//
// Round 17 = round-16 TU (verified reproduction of r9: total 155.1µs,
// GEMM 114.9µs, MfmaUtil 38%, VGPR 124, FETCH 37MB, WRITE 16KB, 0 bank
// conflicts) + r12's PROVEN memset fusion into csplit (packed + loss init;
// passed r12/r13/r14 with identical absmax). GEMM kernel source and launch
// are byte-for-byte r16 — it sits at 124 VGPR + 128 AGPR = 252/256 regs and
// its loop structure is part of the configuration (r15 lesson). Do NOT
// modify the GEMM piecewise: r10-r14 documented that every local
// perturbation (fat phase, barrier cut, smaller wave tiles, X/Y frag dbuf)
// spills or loses to this config.

typedef __attribute__((ext_vector_type(8))) short bf16x8;
typedef __attribute__((ext_vector_type(4))) float f32x4;

#define GL2LDS(g, l) __builtin_amdgcn_global_load_lds( \
    (__attribute__((address_space(1))) const void*)(g), \
    (__attribute__((address_space(3))) void*)(l), 16, 0, 0)

__device__ __forceinline__ unsigned short rne_bf16(float f) {
    unsigned u = __float_as_uint(f);
    return (unsigned short)((u + 0x7FFFu + ((u >> 16) & 1u)) >> 16);
}
__device__ __forceinline__ float bf16_to_f(unsigned short h) {
    return __uint_as_float((unsigned)h << 16);
}

// ---------------------------------------------------------------------------
// codebook row norms ||c_k||^2  (summation order feeds argmin -- unchanged)
// ---------------------------------------------------------------------------
__global__ __launch_bounds__(256)
void vq_cnorm_kernel(const float* __restrict__ cb, float* __restrict__ cnorm)
{
    const int k = blockIdx.x * 256 + threadIdx.x;  // grid=4
    const float4* row = reinterpret_cast<const float4*>(cb + (size_t)k * 256);
    float s0 = 0.f, s1 = 0.f, s2 = 0.f, s3 = 0.f;
#pragma unroll 8
    for (int i = 0; i < 64; ++i) {
        float4 v = row[i];
        s0 = fmaf(v.x, v.x, s0);
        s1 = fmaf(v.y, v.y, s1);
        s2 = fmaf(v.z, v.z, s2);
        s3 = fmaf(v.w, v.w, s3);
    }
    cnorm[k] = (s0 + s1) + (s2 + s3);
}

// ---------------------------------------------------------------------------
// codebook split + packed/loss init (memset fusion, proven r12-r14): grid 256
// ---------------------------------------------------------------------------
__global__ __launch_bounds__(256)
void vq_csplit_kernel(const float* __restrict__ cb, unsigned short* __restrict__ c0,
                      unsigned short* __restrict__ c1, unsigned short* __restrict__ c2,
                      unsigned long long* __restrict__ packed, float* __restrict__ loss)
{
    const int b = blockIdx.x, t = threadIdx.x;
    const int idx = b * 256 + t;
    // fused init (replaces two hipMemsetAsync dispatches)
    if (t < 128) packed[b * 128 + t] = 0xFFFFFFFFFFFFFFFFull;
    if (b == 0 && t == 255) *loss = 0.f;

    float4 v = reinterpret_cast<const float4*>(cb)[idx];
    float f[4] = { v.x, v.y, v.z, v.w };
    ushort4 h0, h1, h2;
    unsigned short* p0[4] = { &h0.x, &h0.y, &h0.z, &h0.w };
    unsigned short* p1[4] = { &h1.x, &h1.y, &h1.z, &h1.w };
    unsigned short* p2[4] = { &h2.x, &h2.y, &h2.z, &h2.w };
#pragma unroll
    for (int j = 0; j < 4; ++j) {
        unsigned short b0 = rne_bf16(f[j]); float r1 = f[j] - bf16_to_f(b0);
        unsigned short b1 = rne_bf16(r1);   float r2 = r1 - bf16_to_f(b1);
        unsigned short b2 = rne_bf16(r2);
        *p0[j] = b0; *p1[j] = b1; *p2[j] = b2;
    }
    reinterpret_cast<ushort4*>(c0)[idx] = h0;
    reinterpret_cast<ushort4*>(c1)[idx] = h1;
    reinterpret_cast<ushort4*>(c2)[idx] = h2;
}

// ---------------------------------------------------------------------------
// z split+transpose: z[b][d][hw] fp32 -> z0,z1,z2 bf16 [n][d]
// ---------------------------------------------------------------------------
__global__ __launch_bounds__(256)
void vq_zsplit_kernel(const float* __restrict__ z, unsigned short* __restrict__ z0,
                      unsigned short* __restrict__ z1, unsigned short* __restrict__ z2)
{
    __shared__ float zl[64 * 264];
    const int t = threadIdx.x, blk = blockIdx.x;        // 512 blocks
    const int b = blk >> 4, hw0 = (blk & 15) << 6;
    const float* zb = z + ((size_t)b << 18) + hw0;
#pragma unroll 8
    for (int i = 0; i < 64; ++i) {
        int idx = i * 256 + t;
        int d = idx >> 6, hwl = idx & 63;
        zl[hwl * 264 + d] = zb[(size_t)d * 1024 + hwl];
    }
    __syncthreads();
    const int n0 = (b << 10) + hw0;
#pragma unroll
    for (int p = 0; p < 8; ++p) {
        const int hwl = p * 8 + (t >> 5);
        const int d0 = (t & 31) * 8;
        const float* src = &zl[hwl * 264 + d0];
        unsigned short h0[8], h1[8], h2[8];
#pragma unroll
        for (int j = 0; j < 8; ++j) {
            float f = src[j];
            unsigned short b0 = rne_bf16(f);  float r1 = f - bf16_to_f(b0);
            unsigned short b1 = rne_bf16(r1); float r2 = r1 - bf16_to_f(b1);
            unsigned short b2 = rne_bf16(r2);
            h0[j] = b0; h1[j] = b1; h2[j] = b2;
        }
        const size_t o = (size_t)(n0 + hwl) * 256 + d0;
        ushort4 a;
        a = ushort4{h0[0],h0[1],h0[2],h0[3]}; *reinterpret_cast<ushort4*>(z0 + o)     = a;
        a = ushort4{h0[4],h0[5],h0[6],h0[7]}; *reinterpret_cast<ushort4*>(z0 + o + 4) = a;
        a = ushort4{h1[0],h1[1],h1[2],h1[3]}; *reinterpret_cast<ushort4*>(z1 + o)     = a;
        a = ushort4{h1[4],h1[5],h1[6],h1[7]}; *reinterpret_cast<ushort4*>(z1 + o + 4) = a;
        a = ushort4{h2[0],h2[1],h2[2],h2[3]}; *reinterpret_cast<ushort4*>(z2 + o)     = a;
        a = ushort4{h2[4],h2[5],h2[6],h2[7]}; *reinterpret_cast<ushort4*>(z2 + o + 4) = a;
    }
}

// ---------------------------------------------------------------------------
// MFMA GEMM + fused argmin — r9/r16 VERBATIM. 256² tile, 8 waves, 4-phase/
// K-tile, counted vmcnt, double-buffered LDS 128KB.
//
// Swizzle (both-sides, rule #21): plane row = 32 bf16 = 64B = 4 chunks;
// bank = (row&1)*16 + slot*4. Store chunk c of row r at slot c ^ ((r>>1)&3)
// (bits 1-2; bit 0 already moves the bank half). gl2lds writes linearly ->
// GLOBAL source chunk pre-swizzled: selem = ((l&3)^((l>>3)&3))*8 (row=l>>2).
// Read: fco = (hi4 ^ ((lo16>>1)&3))*8 (row ≡ lo16 mod 16). Audit: 16-lane
// phase covers all 8 (parity,slot) bank groups exactly 2x = b128 floor.
// ---------------------------------------------------------------------------
__global__ __launch_bounds__(512, 2)
void vq_mfma_argmin_kernel(const unsigned short* __restrict__ zp,
                           const unsigned short* __restrict__ cp,
                           const float* __restrict__ cnorm,
                           unsigned long long* __restrict__ packed)
{
    __shared__ unsigned short Ld[2][2][2][256 * 32];   // 128KB

    const int tid = threadIdx.x, l = tid & 63, w = tid >> 6;
    const int wr = w >> 2, wc = w & 3;                 // 2 x 4 wave grid
    const int nid = ((blockIdx.x & 7) << 6) | (blockIdx.x >> 3);  // XCD swizzle (512%8==0)
    const int bm = nid >> 2, bn = nid & 3;             // 128 x 4 tiles
    const int arow = bm * 256, brow = bn * 256;

    f32x4 acc[8][4];
#pragma unroll
    for (int m = 0; m < 8; ++m)
#pragma unroll
        for (int n = 0; n < 4; ++n) acc[m][n] = f32x4{0.f, 0.f, 0.f, 0.f};

    // staging lane geometry: lane l -> row l>>2, slot l&3; source chunk
    // pre-swizzled by row bits 1-2 ((l>>3)&3) so stored slot = c ^ ((r>>1)&3)
    const int srow  = l >> 2;
    const int selem = (((l & 3) ^ ((l >> 3) & 3))) << 3;

    // fragment-read: chunk hi4 of row r at slot hi4 ^ ((r>>1)&3); r ≡ lo16 (16)
    const int lo16 = l & 15, hi4 = l >> 4;
    const int fco = ((hi4 ^ ((lo16 >> 1) & 3))) << 3;

    // segment tables packed as nibbles: A {0,1,2,0,1,0}, B {0,0,0,1,1,2}
#define STAGE(tt, mat, kk) do {                                               \
    const int seg_ = (tt) >> 2;                                               \
    const unsigned short* S_ = (mat)                                          \
        ? cp + (size_t)((0x211000 >> (seg_ << 2)) & 3) * 262144u              \
        : zp + (size_t)((0x010210 >> (seg_ << 2)) & 3) * 8388608u;            \
    const int R_  = (mat) ? brow : arow;                                      \
    const int KO_ = (((tt) & 3) << 6) + ((kk) << 5) + selem;                  \
    GL2LDS(S_ + (size_t)(R_ + (w * 2 + 0) * 16 + srow) * 256 + KO_,           \
           &Ld[(tt) & 1][mat][kk][(w * 2 + 0) * 512]);                        \
    GL2LDS(S_ + (size_t)(R_ + (w * 2 + 1) * 16 + srow) * 256 + KO_,           \
           &Ld[(tt) & 1][mat][kk][(w * 2 + 1) * 512]);                        \
} while (0)

#define VM12 asm volatile("s_waitcnt vmcnt(12)" ::: "memory")
#define VM8  asm volatile("s_waitcnt vmcnt(8)"  ::: "memory")
#define VM4  asm volatile("s_waitcnt vmcnt(4)"  ::: "memory")
#define VM0  asm volatile("s_waitcnt vmcnt(0)"  ::: "memory")
#define NOPS ((void)0)
#define SBAR do { asm volatile("" ::: "memory");                              \
                  __builtin_amdgcn_s_barrier();                               \
                  __builtin_amdgcn_sched_barrier(0); } while (0)

    bf16x8 bfr0, bfr1, bfr2, bfr3;   // B frags, loaded at mh==0, reused mh==1

#define PH(t, mh, kk, STAGESTMT, VMSTMT) do {                                 \
    const unsigned short* Ap_ = &Ld[(t) & 1][0][kk][0];                       \
    const unsigned short* Bp_ = &Ld[(t) & 1][1][kk][0];                       \
    bf16x8 a0, a1, a2, a3;                                                    \
    a0 = *(const bf16x8*)&Ap_[(wr*128 + ((mh)*4+0)*16 + lo16)*32 + fco];      \
    a1 = *(const bf16x8*)&Ap_[(wr*128 + ((mh)*4+1)*16 + lo16)*32 + fco];      \
    a2 = *(const bf16x8*)&Ap_[(wr*128 + ((mh)*4+2)*16 + lo16)*32 + fco];      \
    a3 = *(const bf16x8*)&Ap_[(wr*128 + ((mh)*4+3)*16 + lo16)*32 + fco];      \
    if ((mh) == 0) {                                                          \
        bfr0 = *(const bf16x8*)&Bp_[(wc*64 + 0*16 + lo16)*32 + fco];          \
        bfr1 = *(const bf16x8*)&Bp_[(wc*64 + 1*16 + lo16)*32 + fco];          \
        bfr2 = *(const bf16x8*)&Bp_[(wc*64 + 2*16 + lo16)*32 + fco];          \
        bfr3 = *(const bf16x8*)&Bp_[(wc*64 + 3*16 + lo16)*32 + fco];          \
    }                                                                         \
    STAGESTMT;                                                                \
    SBAR;                                                                     \
    __builtin_amdgcn_s_setprio(1);                                            \
    acc[(mh)*4+0][0] = __builtin_amdgcn_mfma_f32_16x16x32_bf16(a0, bfr0, acc[(mh)*4+0][0], 0,0,0); \
    acc[(mh)*4+0][1] = __builtin_amdgcn_mfma_f32_16x16x32_bf16(a0, bfr1, acc[(mh)*4+0][1], 0,0,0); \
    acc[(mh)*4+0][2] = __builtin_amdgcn_mfma_f32_16x16x32_bf16(a0, bfr2, acc[(mh)*4+0][2], 0,0,0); \
    acc[(mh)*4+0][3] = __builtin_amdgcn_mfma_f32_16x16x32_bf16(a0, bfr3, acc[(mh)*4+0][3], 0,0,0); \
    acc[(mh)*4+1][0] = __builtin_amdgcn_mfma_f32_16x16x32_bf16(a1, bfr0, acc[(mh)*4+1][0], 0,0,0); \
    acc[(mh)*4+1][1] = __builtin_amdgcn_mfma_f32_16x16x32_bf16(a1, bfr1, acc[(mh)*4+1][1], 0,0,0); \
    acc[(mh)*4+1][2] = __builtin_amdgcn_mfma_f32_16x16x32_bf16(a1, bfr2, acc[(mh)*4+1][2], 0,0,0); \
    acc[(mh)*4+1][3] = __builtin_amdgcn_mfma_f32_16x16x32_bf16(a1, bfr3, acc[(mh)*4+1][3], 0,0,0); \
    acc[(mh)*4+2][0] = __builtin_amdgcn_mfma_f32_16x16x32_bf16(a2, bfr0, acc[(mh)*4+2][0], 0,0,0); \
    acc[(mh)*4+2][1] = __builtin_amdgcn_mfma_f32_16x16x32_bf16(a2, bfr1, acc[(mh)*4+2][1], 0,0,0); \
    acc[(mh)*4+2][2] = __builtin_amdgcn_mfma_f32_16x16x32_bf16(a2, bfr2, acc[(mh)*4+2][2], 0,0,0); \
    acc[(mh)*4+2][3] = __builtin_amdgcn_mfma_f32_16x16x32_bf16(a2, bfr3, acc[(mh)*4+2][3], 0,0,0); \
    acc[(mh)*4+3][0] = __builtin_amdgcn_mfma_f32_16x16x32_bf16(a3, bfr0, acc[(mh)*4+3][0], 0,0,0); \
    acc[(mh)*4+3][1] = __builtin_amdgcn_mfma_f32_16x16x32_bf16(a3, bfr1, acc[(mh)*4+3][1], 0,0,0); \
    acc[(mh)*4+3][2] = __builtin_amdgcn_mfma_f32_16x16x32_bf16(a3, bfr2, acc[(mh)*4+3][2], 0,0,0); \
    acc[(mh)*4+3][3] = __builtin_amdgcn_mfma_f32_16x16x32_bf16(a3, bfr3, acc[(mh)*4+3][3], 0,0,0); \
    __builtin_amdgcn_s_setprio(0);                                            \
    VMSTMT;                                                                   \
    SBAR;                                                                     \
} while (0)

#define TILE(t, SA0, SB0, SA1, SB1, V2, V4)                                   \
    PH(t, 0, 0, SA0, NOPS);                                                   \
    PH(t, 1, 0, SB0, V2);                                                     \
    PH(t, 0, 1, SA1, NOPS);                                                   \
    PH(t, 1, 1, SB1, V4)

    // prologue: stage tiles 0 and 1 (kh0 before kh1); wait tile0-kh0 only
    STAGE(0, 0, 0); STAGE(0, 1, 0); STAGE(0, 0, 1); STAGE(0, 1, 1);
    STAGE(1, 0, 0); STAGE(1, 1, 0); STAGE(1, 0, 1); STAGE(1, 1, 1);
    VM12;
    SBAR;

    TILE(0, NOPS, NOPS, NOPS, NOPS, VM8, VM4);
#pragma unroll 2
    for (int t = 1; t <= 22; ++t) {
        TILE(t, STAGE(t + 1, 0, 0), STAGE(t + 1, 1, 0),
                STAGE(t + 1, 0, 1), STAGE(t + 1, 1, 1), VM4, VM4);
    }
    TILE(23, NOPS, NOPS, NOPS, NOPS, VM0, NOPS);

#undef TILE
#undef PH
#undef STAGE

    // epilogue: fused argmin. col = brow + wc*64 + n*16 + lo16
    int coln[4]; float cnv[4];
#pragma unroll
    for (int n = 0; n < 4; ++n) {
        coln[n] = brow + wc * 64 + n * 16 + lo16;
        cnv[n] = cnorm[coln[n]];
    }
#pragma unroll
    for (int m = 0; m < 8; ++m) {
#pragma unroll
        for (int j = 0; j < 4; ++j) {
            unsigned long long best = 0xFFFFFFFFFFFFFFFFull;
#pragma unroll
            for (int n = 0; n < 4; ++n) {
                float d = fmaf(-2.0f, acc[m][n][j], cnv[n]);
                unsigned u = __float_as_uint(d);
                u = (u & 0x80000000u) ? ~u : (u | 0x80000000u);   // order-preserving map
                unsigned long long pk = ((unsigned long long)u << 32) | (unsigned)coln[n];
                best = pk < best ? pk : best;
            }
#pragma unroll
            for (int mask = 1; mask <= 8; mask <<= 1) {
                unsigned long long o = __shfl_xor(best, mask, 64);
                best = o < best ? o : best;
            }
            if (lo16 == 0) {
                const int row = arow + wr * 128 + m * 16 + hi4 * 4 + j;
                atomicMin(&packed[row], best);
            }
        }
    }
}

// ---------------------------------------------------------------------------
// gather (packed): z_q write, out_idx write, vq_loss accumulate
// ---------------------------------------------------------------------------
__global__ __launch_bounds__(256, 2)
void vq_gather_packed_kernel(const float* __restrict__ cb, const float* __restrict__ z,
                             const unsigned long long* __restrict__ packed,
                             float* __restrict__ out_zq, float* __restrict__ out_idx,
                             float* __restrict__ loss)
{
    __shared__ float rows[64 * 257];
    __shared__ int   ks[64];
    __shared__ float wsum[4];

    const int t   = threadIdx.x;
    const int blk = blockIdx.x;            // 512 blocks
    const int b   = blk >> 4;
    const int hw0 = (blk & 15) << 6;
    const int n0  = blk << 6;

    if (t < 64) {
        const int k = (int)(packed[n0 + t] & 0xFFFFFFFFull);
        ks[t] = k;
        out_idx[n0 + t] = (float)k;
    }
    __syncthreads();

#pragma unroll 4
    for (int i = 0; i < 64; ++i) {
        rows[i * 257 + t] = cb[(size_t)ks[i] * 256 + t];
    }
    __syncthreads();

    const int dq = t >> 6;
    const int hw = t & 63;
    const size_t obase = ((size_t)b << 18) + hw0 + hw;
    float sum = 0.f;
#pragma unroll 4
    for (int dd = 0; dd < 64; ++dd) {
        const int d = (dq << 6) + dd;
        const float  q  = rows[hw * 257 + d];
        const size_t a  = obase + (size_t)d * 1024;
        const float  zv = z[a];
        out_zq[a] = q;
        const float diff = q - zv;
        sum = fmaf(diff, diff, sum);
    }
#pragma unroll
    for (int m = 1; m <= 32; m <<= 1) sum += __shfl_xor(sum, m, 64);
    if ((t & 63) == 0) wsum[t >> 6] = sum;
    __syncthreads();
    if (t == 0) {
        const float s = (wsum[0] + wsum[1]) + (wsum[2] + wsum[3]);
        atomicAdd(loss, s * (1.25f / 8388608.0f));   // (1+0.25)*SSE/(B*D*H*W)
    }
}

// ===========================================================================
// FALLBACK PATH (ws too small): round-3 fp32 VALU kernels, known-passing.
// ===========================================================================
__global__ __launch_bounds__(256)
void vq_transpose_kernel(const float* __restrict__ cb, float* __restrict__ ctT)
{
    __shared__ float tile[64 * 65];
    const int t  = threadIdx.x;
    const int kb = blockIdx.x >> 2, db = blockIdx.x & 3;
    const int k0 = kb << 6, d0 = db << 6;
#pragma unroll
    for (int i = 0; i < 16; ++i) {
        int idx = i * 256 + t;
        int r = idx >> 6, c = idx & 63;
        tile[r * 65 + c] = cb[(size_t)(k0 + r) * 256 + d0 + c];
    }
    __syncthreads();
#pragma unroll
    for (int i = 0; i < 16; ++i) {
        int idx = i * 256 + t;
        int r = idx >> 6, c = idx & 63;
        ctT[(size_t)(d0 + r) * 1024 + k0 + c] = tile[c * 65 + r];
    }
}

__global__ __launch_bounds__(512, 2)
void vq_argmin_kernel(const float* __restrict__ z, const float* __restrict__ ctT,
                      const float* __restrict__ cnorm, int* __restrict__ codes,
                      float* __restrict__ out_idx)
{
    __shared__ float zt[256 * 64];
    __shared__ float ct[16 * 256];
    const int t = threadIdx.x, tx = t & 63, ty = t >> 6, p0 = ty << 3;
    const int blk = blockIdx.x, b = blk >> 4, hw0 = (blk & 15) << 6;
    const float* zbase = z + ((size_t)b << 18) + hw0;
#pragma unroll
    for (int i = 0; i < 8; ++i) {
        int idx = i * 512 + t;
        int d = idx >> 4, c4 = (idx & 15) << 2;
        float4 v = *reinterpret_cast<const float4*>(zbase + (size_t)d * 1024 + c4);
        *reinterpret_cast<float4*>(&zt[d * 64 + c4]) = v;
    }
    float minv[8]; int mini[8];
#pragma unroll
    for (int i = 0; i < 8; ++i) { minv[i] = 3.0e38f; mini[i] = 0; }
    const float* zrd = &zt[p0];
    const float* crd = &ct[tx << 2];
    for (int kt = 0; kt < 4; ++kt) {
        const int k0 = kt << 8;
        float acc[8][4];
#pragma unroll
        for (int i = 0; i < 8; ++i)
#pragma unroll
            for (int j = 0; j < 4; ++j) acc[i][j] = 0.f;
        for (int dc = 0; dc < 16; ++dc) {
            const int d0 = dc << 4;
            __syncthreads();
#pragma unroll
            for (int i = 0; i < 2; ++i) {
                int idx = i * 512 + t;
                int r = idx >> 6, c4 = (idx & 63) << 2;
                float4 v = *reinterpret_cast<const float4*>(ctT + (size_t)(d0 + r) * 1024 + k0 + c4);
                *reinterpret_cast<float4*>(&ct[r * 256 + c4]) = v;
            }
            __syncthreads();
            const float* zp = zrd + d0 * 64;
#pragma unroll
            for (int d = 0; d < 16; ++d) {
                float4 za = *reinterpret_cast<const float4*>(zp + d * 64);
                float4 zb = *reinterpret_cast<const float4*>(zp + d * 64 + 4);
                float4 cc = *reinterpret_cast<const float4*>(crd + d * 256);
#define VQ_FMA_ROW(ii, zv)                          \
                acc[ii][0] = fmaf(zv, cc.x, acc[ii][0]); \
                acc[ii][1] = fmaf(zv, cc.y, acc[ii][1]); \
                acc[ii][2] = fmaf(zv, cc.z, acc[ii][2]); \
                acc[ii][3] = fmaf(zv, cc.w, acc[ii][3]);
                VQ_FMA_ROW(0, za.x) VQ_FMA_ROW(1, za.y) VQ_FMA_ROW(2, za.z) VQ_FMA_ROW(3, za.w)
                VQ_FMA_ROW(4, zb.x) VQ_FMA_ROW(5, zb.y) VQ_FMA_ROW(6, zb.z) VQ_FMA_ROW(7, zb.w)
#undef VQ_FMA_ROW
            }
        }
#pragma unroll
        for (int j = 0; j < 4; ++j) {
            const int k = k0 + (tx << 2) + j;
            const float cn = cnorm[k];
#pragma unroll
            for (int i = 0; i < 8; ++i) {
                float dist = fmaf(-2.0f, acc[i][j], cn);
                if (dist < minv[i]) { minv[i] = dist; mini[i] = k; }
            }
        }
    }
#pragma unroll
    for (int m = 1; m <= 32; m <<= 1) {
#pragma unroll
        for (int i = 0; i < 8; ++i) {
            float ov = __shfl_xor(minv[i], m, 64);
            int   oi = __shfl_xor(mini[i], m, 64);
            if (ov < minv[i] || (ov == minv[i] && oi < mini[i])) { minv[i] = ov; mini[i] = oi; }
        }
    }
    if (tx == 0) {
        const int n0 = (blk << 6) + p0;
#pragma unroll
        for (int i = 0; i < 8; ++i) {
            codes[n0 + i]   = mini[i];
            out_idx[n0 + i] = (float)mini[i];
        }
    }
}

__global__ __launch_bounds__(256, 2)
void vq_gather_kernel(const float* __restrict__ cb, const float* __restrict__ z,
                      const int* __restrict__ codes, float* __restrict__ out_zq,
                      float* __restrict__ loss)
{
    __shared__ float rows[64 * 257];
    __shared__ int   ks[64];
    __shared__ float wsum[4];
    const int t = threadIdx.x, blk = blockIdx.x;
    const int b = blk >> 4, hw0 = (blk & 15) << 6, n0 = blk << 6;
    if (t < 64) ks[t] = codes[n0 + t];
    __syncthreads();
#pragma unroll 4
    for (int i = 0; i < 64; ++i) rows[i * 257 + t] = cb[(size_t)ks[i] * 256 + t];
    __syncthreads();
    const int dq = t >> 6, hw = t & 63;
    const size_t obase = ((size_t)b << 18) + hw0 + hw;
    float sum = 0.f;
#pragma unroll 4
    for (int dd = 0; dd < 64; ++dd) {
        const int d = (dq << 6) + dd;
        const float  q  = rows[hw * 257 + d];
        const size_t a  = obase + (size_t)d * 1024;
        const float  zv = z[a];
        out_zq[a] = q;
        const float diff = q - zv;
        sum = fmaf(diff, diff, sum);
    }
#pragma unroll
    for (int m = 1; m <= 32; m <<= 1) sum += __shfl_xor(sum, m, 64);
    if ((t & 63) == 0) wsum[t >> 6] = sum;
    __syncthreads();
    if (t == 0) {
        const float s = (wsum[0] + wsum[1]) + (wsum[2] + wsum[3]);
        atomicAdd(loss, s * (1.25f / 8388608.0f));
    }
}

// ---------------------------------------------------------------------------
extern "C" void kernel_launch(void* const* d_in, const int* in_sizes, int n_in,
                              void* d_out, int out_size, void* d_ws, size_t ws_size,
                              hipStream_t stream)
{
    (void)in_sizes; (void)n_in; (void)out_size;

    const float* z  = (const float*)d_in[0];   // 32*256*32*32 fp32
    const float* cb = (const float*)d_in[1];   // 1024*256 fp32

    float* out      = (float*)d_out;
    float* out_zq   = out;                     // 8388608
    float* out_idx  = out + 8388608;           // 32768 (indices as float values)
    float* out_loss = out + 8421376;           // 1

    // MFMA-path workspace: packed(256KB) | z0|z1|z2 (16MB each) | c0|c1|c2 | cnorm
    const size_t NEED = 262144ull + 3ull * 16777216ull + 3ull * 524288ull + 4096ull;

    if (ws_size >= NEED) {
        unsigned long long* packed = (unsigned long long*)d_ws;
        unsigned short* z0 = (unsigned short*)((char*)d_ws + 262144);
        unsigned short* z1 = z0 + 8388608u;
        unsigned short* z2 = z1 + 8388608u;
        unsigned short* c0 = z2 + 8388608u;
        unsigned short* c1 = c0 + 262144u;
        unsigned short* c2 = c1 + 262144u;
        float* cnorm = (float*)(c2 + 262144u);

        vq_csplit_kernel<<<256, 256, 0, stream>>>(cb, c0, c1, c2, packed, out_loss);
        vq_cnorm_kernel<<<4, 256, 0, stream>>>(cb, cnorm);
        vq_zsplit_kernel<<<512, 256, 0, stream>>>(z, z0, z1, z2);
        vq_mfma_argmin_kernel<<<512, 512, 0, stream>>>(z0, c0, cnorm, packed);
        vq_gather_packed_kernel<<<512, 256, 0, stream>>>(cb, z, packed, out_zq, out_idx, out_loss);
    } else {
        // fallback: round-3 fp32 path (ws >= 1.38MB known OK)
        float* ctT   = (float*)d_ws;
        float* cnorm = ctT + 256 * 1024;
        int*   codes = (int*)(cnorm + 1024);

        hipMemsetAsync(out_loss, 0, sizeof(float), stream);
        vq_transpose_kernel<<<64, 256, 0, stream>>>(cb, ctT);
        vq_cnorm_kernel<<<4, 256, 0, stream>>>(cb, cnorm);
        vq_argmin_kernel<<<512, 512, 0, stream>>>(z, ctT, cnorm, codes, out_idx);
        vq_gather_kernel<<<512, 256, 0, stream>>>(cb, z, codes, out_zq, out_loss);
    }
}